// Round 2
// baseline (249.595 us; speedup 1.0000x reference)
//
#include <hip/hip_runtime.h>

#define HH 32
#define WW 32
#define CIN 64
#define COUT 64
#define BATCH 32
#define KTOT 576            // CIN * 9
#define NPOS 1024
#define KC 32               // k-chunk
#define NCHUNK 18           // 576 / 32
#define WSTRIDE 260         // 8 o-rows * 32 k + 4 floats pad (breaks 8-way bank conflict)

// halo-padded transposed input: xT[i][34][34][b]
__device__ float g_xT[CIN * 34 * 34 * BATCH];

__global__ void repack_kernel(const float* __restrict__ x) {
    int t = blockIdx.x * blockDim.x + threadIdx.x;   // exactly 64*34*34*32 threads
    int b  = t & 31;
    int s  = t >> 5;          // i*34*34 + hh*34 + ww
    int ww = s % 34;
    int s2 = s / 34;
    int hh = s2 % 34;
    int i  = s2 / 34;
    float v = 0.f;
    int hs = hh - 1, ws = ww - 1;
    if (hs >= 0 && hs < HH && ws >= 0 && ws < WW)
        v = x[(((b << 6) + i) << 10) + (hs << 5) + ws];
    g_xT[t] = v;
}

__device__ __forceinline__ void async16(const void* src, void* dst_lds) {
    __builtin_amdgcn_global_load_lds(
        (const __attribute__((address_space(1))) void*)src,
        (__attribute__((address_space(3))) void*)dst_lds,
        16, 0, 0);
}

__global__ __launch_bounds__(64) void local2d_kernel(
    const float* __restrict__ weight,
    const float* __restrict__ bias,
    float* __restrict__ out)
{
    __shared__ float Wl[2][8 * WSTRIDE];   // [buf][o-group(8) x (8 o x 32 k + pad)]
    __shared__ float Pl[2][KC * BATCH];    // [buf][k(32) x b(32)]

    const int l    = threadIdx.x;          // 0..63, one wave
    const int lrow = l >> 3, lcol = l & 7; // staging roles
    const int og   = l & 7,  bg   = l >> 3; // compute roles: o-group, b-group

    // swizzle: 16 consecutive-w positions -> same XCD (blockIdx % 8 = XCD)
    int bid = blockIdx.x;
    int xcd = bid & 7;
    int t   = bid >> 3;
    int m   = t & 15;
    int gq  = t >> 4;
    int p   = ((gq << 3) + xcd) * 16 + m;  // position = y*32 + x
    int y   = p >> 5, xw = p & 31;

    const float* wpos  = weight + (long)p * (COUT * KTOT);
    const float* wsrc0 = wpos + lrow * KTOT + (lcol << 2);

    float acc[8][4];
#pragma unroll
    for (int a = 0; a < 8; ++a)
#pragma unroll
        for (int c = 0; c < 4; ++c) acc[a][c] = 0.f;

    auto stage = [&](int c, int bsel) {
        // W chunk: 64 o x 32 k, one DMA per 8-o group (8 rows x 128 B = 1024 B contig)
        const float* ws = wsrc0 + c * KC;
#pragma unroll
        for (int g = 0; g < 8; ++g)
            async16(ws + g * (8 * KTOT), &Wl[bsel][g * WSTRIDE]);
        // P chunk: 32 k x 32 b, one DMA per 8 k-rows
#pragma unroll
        for (int q = 0; q < 4; ++q) {
            int k  = c * KC + (q << 3) + lrow;
            int i  = k / 9;
            int r  = k - i * 9;
            int kh = r / 3;
            int kw = r - kh * 3;
            const float* ps =
                &g_xT[(((i * 34) + y + kh) * 34 + xw + kw) * BATCH + (lcol << 2)];
            async16(ps, &Pl[bsel][q * (8 * BATCH)]);
        }
    };

    auto compute = [&](int bsel) {
        const float* Wb = &Wl[bsel][og * WSTRIDE];
        const float* Pb = &Pl[bsel][bg << 2];
#pragma unroll
        for (int kk = 0; kk < KC; kk += 4) {
            float4 pr[4];
#pragma unroll
            for (int j = 0; j < 4; ++j)
                pr[j] = *(const float4*)(Pb + (kk + j) * BATCH);
            const float* prf = (const float*)pr;   // prf[j*4+bb] = P[kk+j][bg*4+bb]
#pragma unroll
            for (int oo = 0; oo < 8; ++oo) {
                float4 wr = *(const float4*)(Wb + oo * 32 + kk); // W[o][kk..kk+3]
#pragma unroll
                for (int bb = 0; bb < 4; ++bb) {
                    float a = acc[oo][bb];
                    a = fmaf(wr.x, prf[0 * 4 + bb], a);
                    a = fmaf(wr.y, prf[1 * 4 + bb], a);
                    a = fmaf(wr.z, prf[2 * 4 + bb], a);
                    a = fmaf(wr.w, prf[3 * 4 + bb], a);
                    acc[oo][bb] = a;
                }
            }
        }
    };

    stage(0, 0);
    stage(1, 1);
    for (int c = 0; c < NCHUNK - 1; ++c) {
        // chunk c's 12 DMAs are the oldest outstanding; <=12 left => c complete
        asm volatile("s_waitcnt vmcnt(12)" ::: "memory");
        compute(c & 1);
        if (c + 2 < NCHUNK) {
            // WAR guard: all prior ds_reads must have SAMPLED the LDS (fully
            // retired) before we issue DMAs that overwrite the buffer
            // compute(c) just read. DMA data lands after issue => race closed.
            asm volatile("s_waitcnt lgkmcnt(0)" ::: "memory");
            stage(c + 2, c & 1);
        }
    }
    asm volatile("s_waitcnt vmcnt(0)" ::: "memory");
    compute((NCHUNK - 1) & 1);

    // epilogue: o = og*8+oo, b = bg*4+bb
#pragma unroll
    for (int oo = 0; oo < 8; ++oo) {
        int o = (og << 3) + oo;
        float bv = bias[(o << 10) + p];
#pragma unroll
        for (int bb = 0; bb < 4; ++bb) {
            int b = (bg << 2) + bb;
            out[(b << 16) + (o << 10) + p] = acc[oo][bb] + bv;
        }
    }
}

extern "C" void kernel_launch(void* const* d_in, const int* in_sizes, int n_in,
                              void* d_out, int out_size, void* d_ws, size_t ws_size,
                              hipStream_t stream) {
    const float* x      = (const float*)d_in[0];
    const float* weight = (const float*)d_in[1];
    const float* bias   = (const float*)d_in[2];
    float* out          = (float*)d_out;

    // 64*34*34*32 = 2,367,488 = 9248 * 256 exactly
    hipLaunchKernelGGL(repack_kernel, dim3(9248), dim3(256), 0, stream, x);
    hipLaunchKernelGGL(local2d_kernel, dim3(NPOS), dim3(64), 0, stream,
                       weight, bias, out);
}

// Round 3
// 246.213 us; speedup vs baseline: 1.0137x; 1.0137x over previous
//
#include <hip/hip_runtime.h>

#define HH 32
#define WW 32
#define CIN 64
#define COUT 64
#define BATCH 32
#define KTOT 576            // CIN * 9
#define NPOS 1024
#define KC 16               // k-chunk per wave-iteration
#define KHALF 288           // K per wave (2-way K-split)
#define NCW 18              // chunks per wave = 288/16
#define WGRP 260            // 16 o-rows * 16 k + 4 floats pad (16B-aligned group stride)

// halo-padded transposed input: xT[i][34][34][b]
__device__ float g_xT[CIN * 34 * 34 * BATCH];

__global__ void repack_kernel(const float* __restrict__ x) {
    int t = blockIdx.x * blockDim.x + threadIdx.x;   // exactly 64*34*34*32 threads
    int b  = t & 31;
    int s  = t >> 5;          // i*34*34 + hh*34 + ww
    int ww = s % 34;
    int s2 = s / 34;
    int hh = s2 % 34;
    int i  = s2 / 34;
    float v = 0.f;
    int hs = hh - 1, ws = ww - 1;
    if (hs >= 0 && hs < HH && ws >= 0 && ws < WW)
        v = x[(((b << 6) + i) << 10) + (hs << 5) + ws];
    g_xT[t] = v;
}

__device__ __forceinline__ void async16(const void* src, void* dst_lds) {
    __builtin_amdgcn_global_load_lds(
        (const __attribute__((address_space(1))) void*)src,
        (__attribute__((address_space(3))) void*)dst_lds,
        16, 0, 0);
}

// 128 threads = 2 waves per block; wave w computes K in [w*288, w*288+288).
// 3-deep LDS pipeline per wave; 6 DMAs per chunk -> vmcnt(6) = prev chunk done.
__global__ __launch_bounds__(128, 2) void local2d_kernel(
    const float* __restrict__ weight,
    const float* __restrict__ bias,
    float* __restrict__ out)
{
    // per-wave private staging: [wave][buf][...]
    __shared__ float Wl[2][3][4 * WGRP];   // 4 groups x (16 o-rows x 16 k + pad)
    __shared__ float Pl[2][3][KC * BATCH]; // 16 k x 32 b

    const int wv = threadIdx.x >> 6;       // wave id 0/1
    const int l  = threadIdx.x & 63;       // lane

    const int og = l & 7, bg = l >> 3;     // compute roles: o-group, b-group

    // swizzle: 16 consecutive-w positions -> same XCD
    int bid = blockIdx.x;
    int xcd = bid & 7;
    int t   = bid >> 3;
    int m   = t & 15;
    int gq  = t >> 4;
    int p   = ((gq << 3) + xcd) * 16 + m;  // position = y*32 + x
    int y   = p >> 5, xw = p & 31;

    const int kbase = wv * KHALF;
    const float* wpos  = weight + (long)p * (COUT * KTOT);
    // W DMA lane role: row l>>2 (of 16-row group), col (l&3)*4 floats
    const float* wsrc0 = wpos + (l >> 2) * KTOT + ((l & 3) << 2) + kbase;

    float acc[8][4];
#pragma unroll
    for (int a = 0; a < 8; ++a)
#pragma unroll
        for (int c = 0; c < 4; ++c) acc[a][c] = 0.f;

    auto stage = [&](int c, int bsel) {
        const float* ws = wsrc0 + c * KC;
        // W chunk: 64 o x 16 k; DMA g covers o-rows [16g,16g+16) = 1024 B contig
#pragma unroll
        for (int g = 0; g < 4; ++g)
            async16(ws + g * (16 * KTOT), &Wl[wv][bsel][g * WGRP]);
        // P chunk: 16 k x 32 b; DMA q covers 8 k-rows = 1024 B contig
#pragma unroll
        for (int q = 0; q < 2; ++q) {
            int k  = kbase + c * KC + (q << 3) + (l >> 3);
            int i  = k / 9;
            int r  = k - i * 9;
            int kh = r / 3;
            int kw = r - kh * 3;
            const float* ps =
                &g_xT[(((i * 34) + y + kh) * 34 + xw + kw) * BATCH + ((l & 7) << 2)];
            async16(ps, &Pl[wv][bsel][q * (8 * BATCH)]);
        }
    };

    auto compute = [&](int bsel) {
        // lane reads o = og*8+oo -> group og>>1, row (og&1)*8+oo
        const float* Wb = &Wl[wv][bsel][(og >> 1) * WGRP + ((og & 1) << 3) * 16];
        const float* Pb = &Pl[wv][bsel][bg << 2];
#pragma unroll
        for (int kk = 0; kk < KC; kk += 4) {
            float4 pr[4];
#pragma unroll
            for (int j = 0; j < 4; ++j)
                pr[j] = *(const float4*)(Pb + (kk + j) * BATCH);
            const float* prf = (const float*)pr;
#pragma unroll
            for (int oo = 0; oo < 8; ++oo) {
                float4 wr = *(const float4*)(Wb + oo * KC + kk);
#pragma unroll
                for (int bb = 0; bb < 4; ++bb) {
                    float a = acc[oo][bb];
                    a = fmaf(wr.x, prf[0 * 4 + bb], a);
                    a = fmaf(wr.y, prf[1 * 4 + bb], a);
                    a = fmaf(wr.z, prf[2 * 4 + bb], a);
                    a = fmaf(wr.w, prf[3 * 4 + bb], a);
                    acc[oo][bb] = a;
                }
            }
        }
    };

    stage(0, 0);
    stage(1, 1);
    for (int c = 0; c < NCW - 1; ++c) {
        // chunk c's 6 DMAs are the oldest; <=6 left => chunk c landed
        asm volatile("s_waitcnt vmcnt(6)" ::: "memory");
        // WAR guard: reads of buf (c+2)%3 were issued in compute(c-1), long
        // retired -> this drain is ~free but guarantees sampling order.
        asm volatile("s_waitcnt lgkmcnt(0)" ::: "memory");
        if (c + 2 < NCW) stage(c + 2, (c + 2) % 3);
        compute(c % 3);
    }
    asm volatile("s_waitcnt vmcnt(0)" ::: "memory");
    compute((NCW - 1) % 3);

    // ---- cross-wave reduction: wave1 dumps partials, wave0 sums + stores ----
    __syncthreads();                       // both waves done with staging bufs
    float* R = &Wl[1][0][0];               // 64 o x 32 b, stride 36 (bank spread)
    if (wv == 1) {
#pragma unroll
        for (int oo = 0; oo < 8; ++oo) {
            int o = (og << 3) + oo;
            *(float4*)(&R[o * 36 + (bg << 2)]) =
                make_float4(acc[oo][0], acc[oo][1], acc[oo][2], acc[oo][3]);
        }
    }
    __syncthreads();
    if (wv == 0) {
#pragma unroll
        for (int oo = 0; oo < 8; ++oo) {
            int o = (og << 3) + oo;
            float bv = bias[(o << 10) + p];
            float4 r = *(const float4*)(&R[o * 36 + (bg << 2)]);
            const float* rf = (const float*)&r;
#pragma unroll
            for (int bb = 0; bb < 4; ++bb) {
                int b = (bg << 2) + bb;
                out[(b << 16) + (o << 10) + p] = acc[oo][bb] + rf[bb] + bv;
            }
        }
    }
}

extern "C" void kernel_launch(void* const* d_in, const int* in_sizes, int n_in,
                              void* d_out, int out_size, void* d_ws, size_t ws_size,
                              hipStream_t stream) {
    const float* x      = (const float*)d_in[0];
    const float* weight = (const float*)d_in[1];
    const float* bias   = (const float*)d_in[2];
    float* out          = (float*)d_out;

    // 64*34*34*32 = 2,367,488 = 9248 * 256 exactly
    hipLaunchKernelGGL(repack_kernel, dim3(9248), dim3(256), 0, stream, x);
    hipLaunchKernelGGL(local2d_kernel, dim3(NPOS), dim3(128), 0, stream,
                       weight, bias, out);
}

// Round 4
// 239.346 us; speedup vs baseline: 1.0428x; 1.0287x over previous
//
#include <hip/hip_runtime.h>

#define HH 32
#define WW 32
#define CIN 64
#define COUT 64
#define BATCH 32
#define KTOT 576            // CIN * 9
#define NPOS 1024
#define KC 16               // k-chunk per wave-iteration
#define KHALF 288           // K per wave (2-way K-split)
#define NCW 18              // chunks per wave = 288/16
#define WGRP 260            // 16 o-rows * 16 k + 4 floats pad (16B-aligned group stride)

// halo-padded transposed input: xT[i][34][34][b]
__device__ float g_xT[CIN * 34 * 34 * BATCH];

// Coalesced transpose repack: one block per (i, hh). Reads x rows (lanes over
// w, 128 B segments), transposes through LDS, writes g_xT rows (lanes over b,
// 128 B segments). Halo rows/cols written as zeros.
__global__ __launch_bounds__(256) void repack_kernel(const float* __restrict__ x) {
    __shared__ float tile[32 * 33];        // [b][w], pad 33 -> conflict-free
    const int i   = blockIdx.x;            // 0..63
    const int hh  = blockIdx.y;            // 0..33
    const int tid = threadIdx.x;

    float* dst = &g_xT[((i * 34 + hh) * 34) * BATCH];

    if (hh == 0 || hh == 33) {             // halo row: all zeros (34*32 floats)
        for (int idx = tid; idx < 34 * BATCH; idx += 256) dst[idx] = 0.f;
        return;
    }
    const int hs = hh - 1;
#pragma unroll
    for (int bb = 0; bb < 4; ++bb) {       // read 8 b-rows per pass
        int b = bb * 8 + (tid >> 5);
        int w = tid & 31;
        tile[b * 33 + w] = x[(b << 16) + (i << 10) + (hs << 5) + w];
    }
    __syncthreads();
#pragma unroll
    for (int q = 0; q < 5; ++q) {          // write 8 ww-rows per pass (34 total)
        int ww = q * 8 + (tid >> 5);
        if (ww < 34) {
            int b = tid & 31;
            float v = (ww == 0 || ww == 33) ? 0.f : tile[b * 33 + (ww - 1)];
            dst[ww * BATCH + b] = v;
        }
    }
}

__device__ __forceinline__ void async16(const void* src, void* dst_lds) {
    __builtin_amdgcn_global_load_lds(
        (const __attribute__((address_space(1))) void*)src,
        (__attribute__((address_space(3))) void*)dst_lds,
        16, 0, 0);
}

// 128 threads = 2 waves per block; wave w computes K in [w*288, w*288+288).
// 3-deep LDS pipeline per wave; 6 DMAs per chunk -> vmcnt(6) = prev chunk done.
__global__ __launch_bounds__(128, 2) void local2d_kernel(
    const float* __restrict__ weight,
    const float* __restrict__ bias,
    float* __restrict__ out)
{
    // per-wave private staging: [wave][buf][...]
    __shared__ float Wl[2][3][4 * WGRP];   // 4 groups x (16 o-rows x 16 k + pad)
    __shared__ float Pl[2][3][KC * BATCH]; // 16 k x 32 b

    const int wv = threadIdx.x >> 6;       // wave id 0/1
    const int l  = threadIdx.x & 63;       // lane

    const int og = l & 7, bg = l >> 3;     // compute roles: o-group, b-group

    // row-granular XCD swizzle: each XCD owns whole output rows ->
    // 32-consecutive-p runs = full 128 B out lines from one XCD; W stream and
    // g_xT row reads contiguous per XCD.
    int bid = blockIdx.x;
    int xcd = bid & 7;
    int t   = bid >> 3;                    // 0..127
    int y   = ((t >> 5) << 3) | xcd;       // {xcd, 8+xcd, 16+xcd, 24+xcd}
    int xw  = t & 31;
    int p   = (y << 5) | xw;               // position = y*32 + x

    const int kbase = wv * KHALF;
    const float* wpos  = weight + (long)p * (COUT * KTOT);
    // W DMA lane role: row l>>2 (of 16-row group), col (l&3)*4 floats
    const float* wsrc0 = wpos + (l >> 2) * KTOT + ((l & 3) << 2) + kbase;

    float acc[8][4];
#pragma unroll
    for (int a = 0; a < 8; ++a)
#pragma unroll
        for (int c = 0; c < 4; ++c) acc[a][c] = 0.f;

    auto stage = [&](int c, int bsel) {
        const float* ws = wsrc0 + c * KC;
        // W chunk: 64 o x 16 k; DMA g covers o-rows [16g,16g+16)
#pragma unroll
        for (int g = 0; g < 4; ++g)
            async16(ws + g * (16 * KTOT), &Wl[wv][bsel][g * WGRP]);
        // P chunk: 16 k x 32 b; DMA q covers 8 k-rows = 1024 B contig
#pragma unroll
        for (int q = 0; q < 2; ++q) {
            int k  = kbase + c * KC + (q << 3) + (l >> 3);
            int i  = k / 9;
            int r  = k - i * 9;
            int kh = r / 3;
            int kw = r - kh * 3;
            const float* ps =
                &g_xT[(((i * 34) + y + kh) * 34 + xw + kw) * BATCH + ((l & 7) << 2)];
            async16(ps, &Pl[wv][bsel][q * (8 * BATCH)]);
        }
    };

    auto compute = [&](int bsel) {
        // lane reads o = og*8+oo -> group og>>1, row (og&1)*8+oo
        const float* Wb = &Wl[wv][bsel][(og >> 1) * WGRP + ((og & 1) << 3) * 16];
        const float* Pb = &Pl[wv][bsel][bg << 2];
#pragma unroll
        for (int kk = 0; kk < KC; kk += 4) {
            float4 pr[4];
#pragma unroll
            for (int j = 0; j < 4; ++j)
                pr[j] = *(const float4*)(Pb + (kk + j) * BATCH);
            const float* prf = (const float*)pr;
#pragma unroll
            for (int oo = 0; oo < 8; ++oo) {
                float4 wr = *(const float4*)(Wb + oo * KC + kk);
#pragma unroll
                for (int bb = 0; bb < 4; ++bb) {
                    float a = acc[oo][bb];
                    a = fmaf(wr.x, prf[0 * 4 + bb], a);
                    a = fmaf(wr.y, prf[1 * 4 + bb], a);
                    a = fmaf(wr.z, prf[2 * 4 + bb], a);
                    a = fmaf(wr.w, prf[3 * 4 + bb], a);
                    acc[oo][bb] = a;
                }
            }
        }
    };

    stage(0, 0);
    stage(1, 1);
    for (int c = 0; c < NCW - 1; ++c) {
        // chunk c's 6 DMAs are the oldest; <=6 left => chunk c landed
        asm volatile("s_waitcnt vmcnt(6)" ::: "memory");
        // WAR guard: reads of buf (c+2)%3 were issued in compute(c-1), long
        // retired -> this drain is ~free but guarantees sampling order.
        asm volatile("s_waitcnt lgkmcnt(0)" ::: "memory");
        if (c + 2 < NCW) stage(c + 2, (c + 2) % 3);
        compute(c % 3);
    }
    asm volatile("s_waitcnt vmcnt(0)" ::: "memory");
    compute((NCW - 1) % 3);

    // ---- cross-wave reduction: wave1 dumps partials, wave0 sums + stores ----
    __syncthreads();                       // both waves done with staging bufs
    float* R = &Wl[1][0][0];               // 64 o x 32 b, stride 36 (bank spread)
    if (wv == 1) {
#pragma unroll
        for (int oo = 0; oo < 8; ++oo) {
            int o = (og << 3) + oo;
            *(float4*)(&R[o * 36 + (bg << 2)]) =
                make_float4(acc[oo][0], acc[oo][1], acc[oo][2], acc[oo][3]);
        }
    }
    __syncthreads();
    if (wv == 0) {
#pragma unroll
        for (int oo = 0; oo < 8; ++oo) {
            int o = (og << 3) + oo;
            float bv = bias[(o << 10) + p];
            float4 r = *(const float4*)(&R[o * 36 + (bg << 2)]);
            const float* rf = (const float*)&r;
#pragma unroll
            for (int bb = 0; bb < 4; ++bb) {
                int b = (bg << 2) + bb;
                out[(b << 16) + (o << 10) + p] = acc[oo][bb] + rf[bb] + bv;
            }
        }
    }
}

extern "C" void kernel_launch(void* const* d_in, const int* in_sizes, int n_in,
                              void* d_out, int out_size, void* d_ws, size_t ws_size,
                              hipStream_t stream) {
    const float* x      = (const float*)d_in[0];
    const float* weight = (const float*)d_in[1];
    const float* bias   = (const float*)d_in[2];
    float* out          = (float*)d_out;

    hipLaunchKernelGGL(repack_kernel, dim3(CIN, 34), dim3(256), 0, stream, x);
    hipLaunchKernelGGL(local2d_kernel, dim3(NPOS), dim3(128), 0, stream,
                       weight, bias, out);
}